// Round 6
// baseline (78.546 us; speedup 1.0000x reference)
//
#include <hip/hip_runtime.h>
#include <stdint.h>

#define IN_F   1024
#define OUT_F  512
#define BATCH  256

// ---------------------------------------------------------------------------
// Kernel A: per (o,i) decide EDGE (argmax idx 0) vs NO_EDGE, pack via ballot.
// Deinterleaved-by-4 layout so kernel B can use the bit-l == lane-l VCC trick
// while keeping float4 x loads:
//   mask_t[o*16 + c*4 + j], bit l  <=>  EDGE at i = c*256 + 4*l + j
//
// Fast path: hardware logf (~1-2 ulp). Guard: if |t1-t0| < 1e-3 (g magnitude
// <= 23 -> logf error <= ~4e-6, so only near-ties are at risk; ~0.1% of
// pairs), recompute numpy's exact f32 op sequence with correctly-rounded
// double logs, including the fl32(e+g) quantization that creates exact
// argmax ties (tie -> index 0 = edge, np.argmax first-max semantics).
// ---------------------------------------------------------------------------
__global__ __launch_bounds__(256) void mask_kernel(
    const float* __restrict__ etc,          // [OUT_F, IN_F, 2]
    const float* __restrict__ un,           // [OUT_F, IN_F, 2]
    unsigned long long* __restrict__ mask_t)// [OUT_F * 16]
{
    int o = blockIdx.x >> 2;
    int c = blockIdx.x & 3;
    int j = threadIdx.x >> 6;   // wave id = sub-position within float4
    int l = threadIdx.x & 63;   // lane = bit position
    int i = c * 256 + l * 4 + j;
    int p = o * IN_F + i;

    float2 e = ((const float2*)etc)[p];
    float2 u = ((const float2*)un)[p];

    // fast f32 path (same op order as numpy, hardware log)
    float s0 = u.x + 1e-10f;
    float t0 = e.x + (-logf(-logf(s0) + 1e-10f));
    float s1 = u.y + 1e-10f;
    float t1 = e.y + (-logf(-logf(s1) + 1e-10f));

    bool no_edge;
    if (__builtin_expect(fabsf(t1 - t0) > 1e-3f, 1)) {
        no_edge = t1 > t0;
    } else {
        // exact numpy-f32 emulation with correctly-rounded logs
        float l0 = (float)log((double)s0);
        float m0 = -l0 + 1e-10f;
        float g0 = -(float)log((double)m0);
        float T0 = e.x + g0;
        float l1 = (float)log((double)s1);
        float m1 = -l1 + 1e-10f;
        float g1 = -(float)log((double)m1);
        float T1 = e.y + g1;
        no_edge = T1 > T0;          // tie -> edge (index 0)
    }

    unsigned long long bits = __ballot(!no_edge);   // 1 = edge
    if (l == 0) mask_t[o * 16 + c * 4 + j] = bits;
}

// ---------------------------------------------------------------------------
// Kernel B: out[b,o] = reduce_i (edge ? x[b,i] : offset), acc init = offset
// (offset is identity AND empty-edge-set result since x in [0,1]).
//
// One wave handles (b, 4 same-parity o's). Lanes span i:
//   lane l holds x[b, c*256 + 4l .. 4l+3] (coalesced float4, 1 KB/instr).
// Select: single VOP3 v_cndmask_b32 with the 64-bit mask word in an SGPR
// pair (bit l <-> lane l). Per-float4 TREE combine (compiler forms
// v_min3/v_max3, breaks the serial acc chain): ~1.75 VALU ops/element.
// Butterfly shfl_xor reduce at the end.
// ---------------------------------------------------------------------------
__device__ __forceinline__ float csel(unsigned long long m, float xv, float sent) {
    float r;
    asm("v_cndmask_b32 %0, %1, %2, %3" : "=v"(r) : "v"(sent), "v"(xv), "s"(m));
    return r;
}

__global__ __launch_bounds__(256, 8) void reduce_kernel(
    const float* __restrict__ x,                   // [BATCH, IN_F]
    const unsigned long long* __restrict__ mask_t, // [OUT_F * 16]
    float* __restrict__ out)                       // [BATCH, OUT_F]
{
    int wave = threadIdx.x >> 6;
    int lane = threadIdx.x & 63;
    int W = blockIdx.x * 4 + wave;                 // 32768 wave-tasks
    int b  = __builtin_amdgcn_readfirstlane(W >> 7);
    int r  = W & 127;
    int parity = __builtin_amdgcn_readfirstlane(r & 1);
    int oq = __builtin_amdgcn_readfirstlane(r >> 1);   // 0..63: group of 4 o's

    const float4* x4 = (const float4*)(x + b * IN_F);

    int o0 = ((oq * 4 + 0) << 1) | parity;
    int o1 = ((oq * 4 + 1) << 1) | parity;
    int o2 = ((oq * 4 + 2) << 1) | parity;
    int o3 = ((oq * 4 + 3) << 1) | parity;
    const unsigned long long* mw0 = mask_t + o0 * 16;
    const unsigned long long* mw1 = mask_t + o1 * 16;
    const unsigned long long* mw2 = mask_t + o2 * 16;
    const unsigned long long* mw3 = mask_t + o3 * 16;

    if (parity == 0) {
        // t-norm: min, offset/sentinel 2.0
        const float S = 2.0f;
        float a0 = S, a1 = S, a2 = S, a3 = S;
        #pragma unroll
        for (int c = 0; c < 4; ++c) {
            float4 xv = x4[c * 64 + lane];
            {   float p0 = fminf(csel(mw0[c*4+0], xv.x, S), csel(mw0[c*4+1], xv.y, S));
                float p1 = fminf(csel(mw0[c*4+2], xv.z, S), csel(mw0[c*4+3], xv.w, S));
                a0 = fminf(a0, fminf(p0, p1)); }
            {   float p0 = fminf(csel(mw1[c*4+0], xv.x, S), csel(mw1[c*4+1], xv.y, S));
                float p1 = fminf(csel(mw1[c*4+2], xv.z, S), csel(mw1[c*4+3], xv.w, S));
                a1 = fminf(a1, fminf(p0, p1)); }
            {   float p0 = fminf(csel(mw2[c*4+0], xv.x, S), csel(mw2[c*4+1], xv.y, S));
                float p1 = fminf(csel(mw2[c*4+2], xv.z, S), csel(mw2[c*4+3], xv.w, S));
                a2 = fminf(a2, fminf(p0, p1)); }
            {   float p0 = fminf(csel(mw3[c*4+0], xv.x, S), csel(mw3[c*4+1], xv.y, S));
                float p1 = fminf(csel(mw3[c*4+2], xv.z, S), csel(mw3[c*4+3], xv.w, S));
                a3 = fminf(a3, fminf(p0, p1)); }
        }
        #pragma unroll
        for (int d = 32; d; d >>= 1) {
            a0 = fminf(a0, __shfl_xor(a0, d, 64));
            a1 = fminf(a1, __shfl_xor(a1, d, 64));
            a2 = fminf(a2, __shfl_xor(a2, d, 64));
            a3 = fminf(a3, __shfl_xor(a3, d, 64));
        }
        if (lane == 0) {
            float* ob = out + b * OUT_F;
            ob[o0] = a0; ob[o1] = a1; ob[o2] = a2; ob[o3] = a3;
        }
    } else {
        // t-conorm: max, offset/sentinel -1.0
        const float S = -1.0f;
        float a0 = S, a1 = S, a2 = S, a3 = S;
        #pragma unroll
        for (int c = 0; c < 4; ++c) {
            float4 xv = x4[c * 64 + lane];
            {   float p0 = fmaxf(csel(mw0[c*4+0], xv.x, S), csel(mw0[c*4+1], xv.y, S));
                float p1 = fmaxf(csel(mw0[c*4+2], xv.z, S), csel(mw0[c*4+3], xv.w, S));
                a0 = fmaxf(a0, fmaxf(p0, p1)); }
            {   float p0 = fmaxf(csel(mw1[c*4+0], xv.x, S), csel(mw1[c*4+1], xv.y, S));
                float p1 = fmaxf(csel(mw1[c*4+2], xv.z, S), csel(mw1[c*4+3], xv.w, S));
                a1 = fmaxf(a1, fmaxf(p0, p1)); }
            {   float p0 = fmaxf(csel(mw2[c*4+0], xv.x, S), csel(mw2[c*4+1], xv.y, S));
                float p1 = fmaxf(csel(mw2[c*4+2], xv.z, S), csel(mw2[c*4+3], xv.w, S));
                a2 = fmaxf(a2, fmaxf(p0, p1)); }
            {   float p0 = fmaxf(csel(mw3[c*4+0], xv.x, S), csel(mw3[c*4+1], xv.y, S));
                float p1 = fmaxf(csel(mw3[c*4+2], xv.z, S), csel(mw3[c*4+3], xv.w, S));
                a3 = fmaxf(a3, fmaxf(p0, p1)); }
        }
        #pragma unroll
        for (int d = 32; d; d >>= 1) {
            a0 = fmaxf(a0, __shfl_xor(a0, d, 64));
            a1 = fmaxf(a1, __shfl_xor(a1, d, 64));
            a2 = fmaxf(a2, __shfl_xor(a2, d, 64));
            a3 = fmaxf(a3, __shfl_xor(a3, d, 64));
        }
        if (lane == 0) {
            float* ob = out + b * OUT_F;
            ob[o0] = a0; ob[o1] = a1; ob[o2] = a2; ob[o3] = a3;
        }
    }
}

extern "C" void kernel_launch(void* const* d_in, const int* in_sizes, int n_in,
                              void* d_out, int out_size, void* d_ws, size_t ws_size,
                              hipStream_t stream) {
    const float* x   = (const float*)d_in[0];  // [BATCH, IN_F]
    const float* etc = (const float*)d_in[1];  // [OUT_F, IN_F, 2]
    const float* un  = (const float*)d_in[2];  // [OUT_F, IN_F, 2]
    float* out = (float*)d_out;                // [BATCH, OUT_F]
    unsigned long long* mask_t = (unsigned long long*)d_ws;  // 64 KB

    // Kernel A: one block per (o, 256-i chunk)
    hipLaunchKernelGGL(mask_kernel, dim3(OUT_F * 4), dim3(256), 0, stream,
                       etc, un, mask_t);
    // Kernel B: 32768 wave-tasks (b x 4 same-parity o's), 4 waves/block
    hipLaunchKernelGGL(reduce_kernel, dim3(BATCH * OUT_F / 4 / 4), dim3(256), 0, stream,
                       x, mask_t, out);
}